// Round 2
// baseline (416.309 us; speedup 1.0000x reference)
//
#include <hip/hip_runtime.h>
#include <hip/hip_bf16.h>
#include <stdint.h>

// SimLinear: C[50,8192] = x[50,8192] @ W[8192,8192]^T + bias
// R6: ZERO workspace use. Profiling showed dur_us was dominated by two
// 1-GiB workspace re-poison fills (~322 us of the 376 us) -- the actual
// compute was already < ~60 us. The packed-XP path (workspace) is removed;
// B-fragments are built from fp32 x on the fly (x is 1.6 MB, L2-resident;
// same bfpair rounding as pack_x so results are bit-identical).
// Geometry unchanged from verified R5: WG = 16 W rows, wave w streams
// K-slice [w*2048,(w+1)*2048) of all 16 rows straight from global with a
// 2-block register double-buffer (no barriers, no vmcnt(0) drain in loop),
// cross-wave k-reduce in LDS at the end.

#define K_DIM  8192
#define O_DIM  8192
#define BATCH  50
#define ROWS   16                 // W rows (outputs) per WG
#define NWG    (O_DIM / ROWS)     // 512 WGs -> 2 per CU
#define KSLICE (K_DIM / 4)        // 2048 fp32 per wave
#define NSTEP  (KSLICE / 32)      // 64 k-steps of 32 fp32
#define U      2                  // steps per pipeline block
#define NBLK   (NSTEP / U)        // 32 blocks (even)

typedef __attribute__((ext_vector_type(8)))  __bf16 bf16x8;
typedef __attribute__((ext_vector_type(4)))  float  f32x4;
typedef __attribute__((ext_vector_type(4)))  int    i32x4;

// fp32 pair -> dword of two bf16 (round-half-up): +0x8000 then high halves.
__device__ __forceinline__ unsigned bfpair(float a, float b) {
    unsigned ua = __float_as_uint(a) + 0x8000u;
    unsigned ub = __float_as_uint(b) + 0x8000u;
    return __builtin_amdgcn_perm(ub, ua, 0x07060302u);  // [a.hi16, b.hi16]
}

__device__ __forceinline__ bf16x8 pack8(float4 lo, float4 hi) {
    i32x4 p;
    p.x = (int)bfpair(lo.x, lo.y);
    p.y = (int)bfpair(lo.z, lo.w);
    p.z = (int)bfpair(hi.x, hi.y);
    p.w = (int)bfpair(hi.z, hi.w);
    return __builtin_bit_cast(bf16x8, p);
}

// Per-block register staging: U steps of raw fp32 A (W rows) + B (x rows).
// Raw fp32 kept in regs; bf16 pack happens at compute time so the loads
// double-buffer cleanly (no VALU between load issue and the next block).
struct AB {
    float4 a0[U], a1[U];          // A: W[obase+l15][k-octet q], 32 B/lane
    float4 x0[U][4], x1[U][4];    // B: x[g*16+l15][k-octet q], 32 B/lane
};

__device__ __forceinline__ void load_blk(AB& t, const float* __restrict__ wp,
                                         const float* const* xb,
                                         const bool* act, int blk) {
    #pragma unroll
    for (int j = 0; j < U; ++j) {
        const float* p = wp + (size_t)(blk * U + j) * 32;
        t.a0[j] = *(const float4*)p;
        t.a1[j] = *(const float4*)(p + 4);
    }
    const float4 z = {0.f, 0.f, 0.f, 0.f};
    #pragma unroll
    for (int j = 0; j < U; ++j)
        #pragma unroll
        for (int g = 0; g < 4; ++g) {
            t.x0[j][g] = z;
            t.x1[j][g] = z;
            if (act[g]) {
                const float* p = xb[g] + (size_t)(blk * U + j) * 32;
                t.x0[j][g] = *(const float4*)p;
                t.x1[j][g] = *(const float4*)(p + 4);
            }
        }
}

__device__ __forceinline__ void comp_blk(const AB& t, f32x4* acc) {
    #pragma unroll
    for (int j = 0; j < U; ++j) {
        bf16x8 af = pack8(t.a0[j], t.a1[j]);
        #pragma unroll
        for (int g = 0; g < 4; ++g)
            acc[g] = __builtin_amdgcn_mfma_f32_16x16x32_bf16(
                         af, pack8(t.x0[j][g], t.x1[j][g]), acc[g], 0, 0, 0);
    }
}

// A[m=lane&15][k = s*32 + (lane>>4)*8 + 0..7]   (2x dwordx4, fp32->bf16)
// B[k][n=batch]: same octet from x[g*16+l15], fp32->bf16 in-loop
// C/D: col=lane&15 (batch), row=(lane>>4)*4+reg (output row)
__global__ __launch_bounds__(256, 2) void simlinear_mfma(
        const float* __restrict__ X,
        const float* __restrict__ W,
        const float* __restrict__ bias,
        float* __restrict__ out) {
    __shared__ float red[4 * 1024];              // 16 KB epilogue reduce

    const int tid   = threadIdx.x;
    const int wave  = tid >> 6;
    const int lane  = tid & 63;
    const int l15   = lane & 15;
    const int q     = lane >> 4;                 // k-octet within step
    const int obase = blockIdx.x * ROWS;

    // Per-lane stream bases: W row l15, x rows g*16+l15, k-slice of this wave.
    const float* wp = W + (size_t)(obase + l15) * K_DIM + wave * KSLICE + q * 8;
    const float* xb[4];
    bool act[4];
    #pragma unroll
    for (int g = 0; g < 4; ++g) {
        const int b = g * 16 + l15;
        act[g] = (b < BATCH);
        xb[g]  = X + (size_t)(act[g] ? b : 0) * K_DIM + wave * KSLICE + q * 8;
    }

    f32x4 acc[4] = {};                           // 4 b-groups x 4 f32

    AB t0, t1;
    load_blk(t0, wp, xb, act, 0);
    #pragma unroll 1
    for (int blk = 0; blk < NBLK; blk += 2) {
        load_blk(t1, wp, xb, act, blk + 1);      // next block in flight
        comp_blk(t0, acc);
        if (blk + 2 < NBLK)
            load_blk(t0, wp, xb, act, blk + 2);
        comp_blk(t1, acc);
    }

    // ---- cross-wave reduce: red[w][b*16+m] ----
    #pragma unroll
    for (int g = 0; g < 4; ++g)
        #pragma unroll
        for (int r = 0; r < 4; ++r)
            red[wave * 1024 + (g * 16 + l15) * 16 + (q * 4 + r)] = acc[g][r];
    __syncthreads();

    #pragma unroll
    for (int it = 0; it < 4; ++it) {
        const int i = it * 256 + tid;            // [0,1024): b = i>>4, m = i&15
        const int b = i >> 4;
        const int m = i & 15;
        float s = red[i] + red[1024 + i] + red[2048 + i] + red[3072 + i];
        if (b < BATCH)
            out[(size_t)b * O_DIM + obase + m] = s + bias[obase + m];
    }
}

extern "C" void kernel_launch(void* const* d_in, const int* in_sizes, int n_in,
                              void* d_out, int out_size, void* d_ws, size_t ws_size,
                              hipStream_t stream) {
    const float* x    = (const float*)d_in[0];
    const float* w    = (const float*)d_in[1];
    const float* bias = (const float*)d_in[2];
    float* out = (float*)d_out;
    (void)d_ws; (void)ws_size;                   // workspace intentionally unused
    simlinear_mfma<<<NWG, 256, 0, stream>>>(x, w, bias, out);
}